// Round 2
// baseline (300.933 us; speedup 1.0000x reference)
//
#include <hip/hip_runtime.h>

#define H_ 1024
#define NH_ 16
#define HD_ 64
#define B_ 2
#define S_ 2048
#define BS_ 4096

typedef _Float16 half8 __attribute__((ext_vector_type(8)));
typedef _Float16 half4_t __attribute__((ext_vector_type(4)));
typedef float floatx4 __attribute__((ext_vector_type(4)));

// ---------------- fp32 -> fp16 conversion (hs + 4 weights) ----------------
__global__ __launch_bounds__(256) void cvt_all(
    const float* __restrict__ hs, const float* __restrict__ wq,
    const float* __restrict__ wk, const float* __restrict__ wv,
    const float* __restrict__ wo,
    _Float16* __restrict__ hs_h, _Float16* __restrict__ w_h) {
  int i = blockIdx.x * 256 + threadIdx.x;
  int idx = i * 4;
  const float* src; _Float16* dst; int off;
  if (idx < BS_ * H_) {
    src = hs; dst = hs_h; off = idx;
  } else {
    int j = idx - BS_ * H_;
    int w = j >> 20;               // each weight is 2^20 elements
    off = j & ((1 << 20) - 1);
    src = (w == 0) ? wq : (w == 1) ? wk : (w == 2) ? wv : wo;
    dst = w_h + (size_t)w * (H_ * H_);
  }
  float4 f = *(const float4*)(src + off);
  half4_t o;
  o.x = (_Float16)f.x; o.y = (_Float16)f.y;
  o.z = (_Float16)f.z; o.w = (_Float16)f.w;
  *(half4_t*)(dst + off) = o;
}

// ---------------- QKV GEMM: C = A @ W^T, elu+1 on q/k, head-major out ------
// grid (8, 32, 3)  block 256.  z: 0=q 1=k 2=v
__global__ __launch_bounds__(256) void qkv_gemm(
    const _Float16* __restrict__ A, const _Float16* __restrict__ Wall,
    _Float16* __restrict__ qh, _Float16* __restrict__ kh,
    _Float16* __restrict__ vh) {
  const int z = blockIdx.z;
  const _Float16* W = Wall + (size_t)z * (H_ * H_);
  _Float16* outp = (z == 0) ? qh : (z == 1) ? kh : vh;
  const int rbase = blockIdx.y * 128;
  const int cbase = blockIdx.x * 128;
  __shared__ _Float16 As[128 * 32];
  __shared__ _Float16 Bs[128 * 32];
  const int tid = threadIdx.x, lane = tid & 63, w = tid >> 6;
  const int quad = lane >> 4, l16 = lane & 15;
  const int wr = (w >> 1) * 64, wc = (w & 1) * 64;

  floatx4 zero = {0.f, 0.f, 0.f, 0.f};
  floatx4 acc[4][4];
#pragma unroll
  for (int i = 0; i < 4; ++i)
#pragma unroll
    for (int j = 0; j < 4; ++j) acc[i][j] = zero;

  for (int k0 = 0; k0 < H_; k0 += 32) {
#pragma unroll
    for (int c = tid; c < 512; c += 256) {
      int row = c >> 2, cl = c & 3;
      *(half8*)&As[row * 32 + cl * 8] =
          *(const half8*)&A[(rbase + row) * H_ + k0 + cl * 8];
      *(half8*)&Bs[row * 32 + cl * 8] =
          *(const half8*)&W[(cbase + row) * H_ + k0 + cl * 8];
    }
    __syncthreads();
    half8 af[4], bf[4];
#pragma unroll
    for (int t = 0; t < 4; ++t)
      af[t] = *(half8*)&As[(wr + t * 16 + l16) * 32 + quad * 8];
#pragma unroll
    for (int t = 0; t < 4; ++t)
      bf[t] = *(half8*)&Bs[(wc + t * 16 + l16) * 32 + quad * 8];
#pragma unroll
    for (int i = 0; i < 4; ++i)
#pragma unroll
      for (int j = 0; j < 4; ++j)
        acc[i][j] = __builtin_amdgcn_mfma_f32_16x16x32_f16(af[i], bf[j],
                                                           acc[i][j], 0, 0, 0);
    __syncthreads();
  }
  // epilogue: optional elu+1, scatter to head-major (B, NH, S, HD)
#pragma unroll
  for (int i = 0; i < 4; ++i) {
    int r0 = rbase + wr + i * 16 + quad * 4;
#pragma unroll
    for (int j = 0; j < 4; ++j) {
      int col = cbase + wc + j * 16 + l16;
      int h = col >> 6, d = col & 63;
#pragma unroll
      for (int r = 0; r < 4; ++r) {
        float x = acc[i][j][r];
        if (z < 2) x = (x > 0.f) ? (x + 1.f) : __expf(x);
        int row = r0 + r;
        int b = row >> 11, sl = row & (S_ - 1);
        outp[((size_t)(b * NH_ + h) * S_ + sl) * HD_ + d] = (_Float16)x;
      }
    }
  }
}

// ---------------- V transpose per head: (bh, s, d) -> (bh, d, s) -----------
// grid (32, 32) block 256
__global__ __launch_bounds__(256) void v_transpose(
    const _Float16* __restrict__ vh, _Float16* __restrict__ vt) {
  int bh = blockIdx.y;
  int s0 = blockIdx.x * 64;
  __shared__ _Float16 t[64 * 72];
  int tid = threadIdx.x;
#pragma unroll
  for (int c = tid; c < 512; c += 256) {
    int r = c >> 3, cl = c & 7;
    *(half8*)&t[r * 72 + cl * 8] =
        *(const half8*)&vh[((size_t)bh * S_ + s0 + r) * 64 + cl * 8];
  }
  __syncthreads();
#pragma unroll
  for (int c = tid; c < 512; c += 256) {
    int d = c >> 3, sc = c & 7;
    half8 vv;
#pragma unroll
    for (int j = 0; j < 8; ++j) vv[j] = t[(sc * 8 + j) * 72 + d];
    *(half8*)&vt[((size_t)bh * 64 + d) * S_ + s0 + sc * 8] = vv;
  }
}

// ---------------- Flash attention ------------------------------------------
// grid (S/64=32, B*NH=32) block 256 (4 waves, 16 q-rows each), BC=128
__global__ __launch_bounds__(256) void flash_attn(
    const _Float16* __restrict__ qh, const _Float16* __restrict__ kh,
    const _Float16* __restrict__ vt, const int* __restrict__ mask,
    _Float16* __restrict__ attn_out) {
  const int bh = blockIdx.y, b = bh >> 4, h = bh & 15;
  const int qbase = blockIdx.x * 64;
  const int tid = threadIdx.x, w = tid >> 6, lane = tid & 63;
  const int quad = lane >> 4, l16 = lane & 15;

  __shared__ _Float16 Kt[128 * 72];        // [key][d], stride 72
  __shared__ _Float16 Vt[64 * 136];        // [d][key], stride 136
  __shared__ _Float16 Pt[4][16 * 136];     // per-wave [qrow][key], stride 136
  __shared__ int mk[128];

  const _Float16* Q = qh + (size_t)bh * (S_ * HD_);
  const _Float16* K = kh + (size_t)bh * (S_ * HD_);
  const _Float16* Vg = vt + (size_t)bh * (HD_ * S_);

  // Q fragments live in registers for the whole kernel
  const int qr = qbase + w * 16 + l16;
  half8 qf0 = *(const half8*)&Q[qr * 64 + quad * 8];
  half8 qf1 = *(const half8*)&Q[qr * 64 + 32 + quad * 8];

  floatx4 zero = {0.f, 0.f, 0.f, 0.f};
  floatx4 o[4];
#pragma unroll
  for (int i = 0; i < 4; ++i) o[i] = zero;
  float mi[4], li[4];
#pragma unroll
  for (int r = 0; r < 4; ++r) { mi[r] = -3e38f; li[r] = 0.f; }

  for (int kt = 0; kt < S_ / 128; ++kt) {
    const int key0 = kt * 128;
    // stage K tile (128 keys x 64 d) = 1024 half8s
#pragma unroll
    for (int c = tid; c < 1024; c += 256) {
      int row = c >> 3, cl = c & 7;
      *(half8*)&Kt[row * 72 + cl * 8] =
          *(const half8*)&K[(key0 + row) * 64 + cl * 8];
    }
    // stage V^T tile (64 d x 128 keys) = 1024 half8s
#pragma unroll
    for (int c = tid; c < 1024; c += 256) {
      int row = c >> 4, cl = c & 15;
      *(half8*)&Vt[row * 136 + cl * 8] =
          *(const half8*)&Vg[row * S_ + key0 + cl * 8];
    }
    if (tid < 128) mk[tid] = mask[b * S_ + key0 + tid];
    __syncthreads();

    // S_tile = Q @ K^T : 16 x 128 per wave
    floatx4 sa[8];
#pragma unroll
    for (int ct = 0; ct < 8; ++ct) sa[ct] = zero;
#pragma unroll
    for (int ct = 0; ct < 8; ++ct) {
      half8 bf0 = *(half8*)&Kt[(ct * 16 + l16) * 72 + quad * 8];
      half8 bf1 = *(half8*)&Kt[(ct * 16 + l16) * 72 + 32 + quad * 8];
      sa[ct] = __builtin_amdgcn_mfma_f32_16x16x32_f16(qf0, bf0, sa[ct], 0, 0, 0);
      sa[ct] = __builtin_amdgcn_mfma_f32_16x16x32_f16(qf1, bf1, sa[ct], 0, 0, 0);
    }
    // mask (col = ct*16 + l16)
#pragma unroll
    for (int ct = 0; ct < 8; ++ct) {
      if (mk[ct * 16 + l16] == 0) {
        sa[ct][0] = -1e30f; sa[ct][1] = -1e30f;
        sa[ct][2] = -1e30f; sa[ct][3] = -1e30f;
      }
    }
    // online softmax per row r (row = quad*4 + r)
    float alpha[4];
#pragma unroll
    for (int r = 0; r < 4; ++r) {
      float mx = sa[0][r];
#pragma unroll
      for (int ct = 1; ct < 8; ++ct) mx = fmaxf(mx, sa[ct][r]);
      mx = fmaxf(mx, __shfl_xor(mx, 1));
      mx = fmaxf(mx, __shfl_xor(mx, 2));
      mx = fmaxf(mx, __shfl_xor(mx, 4));
      mx = fmaxf(mx, __shfl_xor(mx, 8));
      float mn = fmaxf(mi[r], mx);
      alpha[r] = __expf(mi[r] - mn);
      mi[r] = mn;
      float rs = 0.f;
#pragma unroll
      for (int ct = 0; ct < 8; ++ct) {
        float p = __expf(sa[ct][r] - mn);
        sa[ct][r] = p;
        rs += p;
      }
      rs += __shfl_xor(rs, 1);
      rs += __shfl_xor(rs, 2);
      rs += __shfl_xor(rs, 4);
      rs += __shfl_xor(rs, 8);
      li[r] = li[r] * alpha[r] + rs;
      o[0][r] *= alpha[r]; o[1][r] *= alpha[r];
      o[2][r] *= alpha[r]; o[3][r] *= alpha[r];
    }
    // P: C-layout -> LDS (per-wave region)
#pragma unroll
    for (int ct = 0; ct < 8; ++ct)
#pragma unroll
      for (int r = 0; r < 4; ++r)
        Pt[w][(quad * 4 + r) * 136 + ct * 16 + l16] = (_Float16)sa[ct][r];
    __syncthreads();  // P write -> read ordering (wave-local, but well-defined)
    // O += P @ V
#pragma unroll
    for (int kk = 0; kk < 4; ++kk) {
      half8 pf = *(half8*)&Pt[w][l16 * 136 + kk * 32 + quad * 8];
#pragma unroll
      for (int ct2 = 0; ct2 < 4; ++ct2) {
        half8 vf = *(half8*)&Vt[(ct2 * 16 + l16) * 136 + kk * 32 + quad * 8];
        o[ct2] = __builtin_amdgcn_mfma_f32_16x16x32_f16(pf, vf, o[ct2], 0, 0, 0);
      }
    }
    __syncthreads();
  }
  // epilogue: normalize, store (B, S, H) fp16
#pragma unroll
  for (int ct2 = 0; ct2 < 4; ++ct2) {
#pragma unroll
    for (int r = 0; r < 4; ++r) {
      int row = qbase + w * 16 + quad * 4 + r;
      int d = ct2 * 16 + l16;
      float val = o[ct2][r] / li[r];
      attn_out[((size_t)(b * S_ + row)) * H_ + h * HD_ + d] = (_Float16)val;
    }
  }
}

// ---------------- Output GEMM: out = AO @ Wo^T (fp32 out) ------------------
// grid (8, 32) block 256
__global__ __launch_bounds__(256) void out_gemm(
    const _Float16* __restrict__ A, const _Float16* __restrict__ W,
    float* __restrict__ out) {
  const int rbase = blockIdx.y * 128;
  const int cbase = blockIdx.x * 128;
  __shared__ _Float16 As[128 * 32];
  __shared__ _Float16 Bs[128 * 32];
  const int tid = threadIdx.x, lane = tid & 63, w = tid >> 6;
  const int quad = lane >> 4, l16 = lane & 15;
  const int wr = (w >> 1) * 64, wc = (w & 1) * 64;

  floatx4 zero = {0.f, 0.f, 0.f, 0.f};
  floatx4 acc[4][4];
#pragma unroll
  for (int i = 0; i < 4; ++i)
#pragma unroll
    for (int j = 0; j < 4; ++j) acc[i][j] = zero;

  for (int k0 = 0; k0 < H_; k0 += 32) {
#pragma unroll
    for (int c = tid; c < 512; c += 256) {
      int row = c >> 2, cl = c & 3;
      *(half8*)&As[row * 32 + cl * 8] =
          *(const half8*)&A[(rbase + row) * H_ + k0 + cl * 8];
      *(half8*)&Bs[row * 32 + cl * 8] =
          *(const half8*)&W[(cbase + row) * H_ + k0 + cl * 8];
    }
    __syncthreads();
    half8 af[4], bf[4];
#pragma unroll
    for (int t = 0; t < 4; ++t)
      af[t] = *(half8*)&As[(wr + t * 16 + l16) * 32 + quad * 8];
#pragma unroll
    for (int t = 0; t < 4; ++t)
      bf[t] = *(half8*)&Bs[(wc + t * 16 + l16) * 32 + quad * 8];
#pragma unroll
    for (int i = 0; i < 4; ++i)
#pragma unroll
      for (int j = 0; j < 4; ++j)
        acc[i][j] = __builtin_amdgcn_mfma_f32_16x16x32_f16(af[i], bf[j],
                                                           acc[i][j], 0, 0, 0);
    __syncthreads();
  }
#pragma unroll
  for (int i = 0; i < 4; ++i) {
    int r0 = rbase + wr + i * 16 + quad * 4;
#pragma unroll
    for (int j = 0; j < 4; ++j) {
      int col = cbase + wc + j * 16 + l16;
#pragma unroll
      for (int r = 0; r < 4; ++r)
        out[(size_t)(r0 + r) * H_ + col] = acc[i][j][r];
    }
  }
}

extern "C" void kernel_launch(void* const* d_in, const int* in_sizes, int n_in,
                              void* d_out, int out_size, void* d_ws,
                              size_t ws_size, hipStream_t stream) {
  const float* hs = (const float*)d_in[0];
  const int* mask = (const int*)d_in[1];
  const float* Wq = (const float*)d_in[2];
  const float* Wk = (const float*)d_in[3];
  const float* Wv = (const float*)d_in[4];
  const float* Wo = (const float*)d_in[5];
  float* out = (float*)d_out;

  _Float16* p = (_Float16*)d_ws;
  _Float16* hs_h = p; p += (size_t)BS_ * H_;        // 4.19M
  _Float16* w_h = p;  p += (size_t)4 * H_ * H_;     // 4 x 1.05M
  _Float16* q_h = p;  p += (size_t)BS_ * H_;
  _Float16* k_h = p;  p += (size_t)BS_ * H_;
  _Float16* v_h = p;  p += (size_t)BS_ * H_;
  _Float16* v_t = p;  p += (size_t)BS_ * H_;
  _Float16* ao_h = p; p += (size_t)BS_ * H_;

  // total floats to convert: 4.19M + 4*1.05M = 8.39M -> /4 per thread
  cvt_all<<<8192, 256, 0, stream>>>(hs, Wq, Wk, Wv, Wo, hs_h, w_h);
  qkv_gemm<<<dim3(8, 32, 3), 256, 0, stream>>>(hs_h, w_h, q_h, k_h, v_h);
  v_transpose<<<dim3(32, 32), 256, 0, stream>>>(v_h, v_t);
  flash_attn<<<dim3(32, 32), 256, 0, stream>>>(q_h, k_h, v_t, mask, ao_h);
  out_gemm<<<dim3(8, 32), 256, 0, stream>>>(ao_h, w_h + (size_t)3 * H_ * H_, out);
}

// Round 3
// 277.042 us; speedup vs baseline: 1.0862x; 1.0862x over previous
//
#include <hip/hip_runtime.h>

#define H_ 1024
#define NH_ 16
#define HD_ 64
#define B_ 2
#define S_ 2048
#define BS_ 4096

typedef _Float16 half8 __attribute__((ext_vector_type(8)));
typedef _Float16 half4_t __attribute__((ext_vector_type(4)));
typedef float floatx4 __attribute__((ext_vector_type(4)));

__device__ __forceinline__ void async_copy16(void* lds, const void* g) {
  __builtin_amdgcn_global_load_lds(
      (const __attribute__((address_space(1))) unsigned int*)g,
      (__attribute__((address_space(3))) unsigned int*)lds, 16, 0, 0);
}

// ---------------- fp32 -> fp16 conversion (hs + 4 weights) ----------------
__global__ __launch_bounds__(256) void cvt_all(
    const float* __restrict__ hs, const float* __restrict__ wq,
    const float* __restrict__ wk, const float* __restrict__ wv,
    const float* __restrict__ wo,
    _Float16* __restrict__ hs_h, _Float16* __restrict__ w_h) {
  int i = blockIdx.x * 256 + threadIdx.x;
  int idx = i * 4;
  const float* src; _Float16* dst; int off;
  if (idx < BS_ * H_) {
    src = hs; dst = hs_h; off = idx;
  } else {
    int j = idx - BS_ * H_;
    int w = j >> 20;               // each weight is 2^20 elements
    off = j & ((1 << 20) - 1);
    src = (w == 0) ? wq : (w == 1) ? wk : (w == 2) ? wv : wo;
    dst = w_h + (size_t)w * (H_ * H_);
  }
  float4 f = *(const float4*)(src + off);
  half4_t o;
  o.x = (_Float16)f.x; o.y = (_Float16)f.y;
  o.z = (_Float16)f.z; o.w = (_Float16)f.w;
  *(half4_t*)(dst + off) = o;
}

// ---------------- QKV GEMM: C = A @ W^T, elu+1 on q/k, head-major out ------
// grid (8, 32, 3)  block 256.  z: 0=q 1=k 2=v.  m97-style global_load_lds.
__global__ __launch_bounds__(256) void qkv_gemm(
    const _Float16* __restrict__ A, const _Float16* __restrict__ Wall,
    _Float16* __restrict__ qh, _Float16* __restrict__ kh,
    _Float16* __restrict__ vh) {
  const int z = blockIdx.z;
  const _Float16* W = Wall + (size_t)z * (H_ * H_);
  _Float16* outp = (z == 0) ? qh : (z == 1) ? kh : vh;
  const int rbase = blockIdx.y * 128;
  const int cbase = blockIdx.x * 128;
  __shared__ _Float16 As[128 * 32];
  __shared__ _Float16 Bs[128 * 32];
  const int tid = threadIdx.x, lane = tid & 63, w = tid >> 6;
  const int quad = lane >> 4, l16 = lane & 15;
  const int wr = (w >> 1) * 64, wc = (w & 1) * 64;

  floatx4 zero = {0.f, 0.f, 0.f, 0.f};
  floatx4 acc[4][4];
#pragma unroll
  for (int i = 0; i < 4; ++i)
#pragma unroll
    for (int j = 0; j < 4; ++j) acc[i][j] = zero;

  // staging addressing: wave w stages rows [w*32, w*32+32) of each tile.
  const int srow = w * 32 + (lane >> 2);       // global row within tile
  const int sseg = (lane & 3) * 8;             // halfs offset within 32-half row
  const _Float16* Ag = A + (size_t)(rbase + srow) * H_ + sseg;
  const _Float16* Bg = W + (size_t)(cbase + srow) * H_ + sseg;

  for (int k0 = 0; k0 < H_; k0 += 32) {
    async_copy16(&As[(w * 32) * 32], Ag + k0);
    async_copy16(&As[(w * 32 + 16) * 32], Ag + 16 * H_ + k0);
    async_copy16(&Bs[(w * 32) * 32], Bg + k0);
    async_copy16(&Bs[(w * 32 + 16) * 32], Bg + 16 * H_ + k0);
    __syncthreads();
    half8 af[4], bf[4];
#pragma unroll
    for (int t = 0; t < 4; ++t)
      af[t] = *(half8*)&As[(wr + t * 16 + l16) * 32 + quad * 8];
#pragma unroll
    for (int t = 0; t < 4; ++t)
      bf[t] = *(half8*)&Bs[(wc + t * 16 + l16) * 32 + quad * 8];
#pragma unroll
    for (int i = 0; i < 4; ++i)
#pragma unroll
      for (int j = 0; j < 4; ++j)
        acc[i][j] = __builtin_amdgcn_mfma_f32_16x16x32_f16(af[i], bf[j],
                                                           acc[i][j], 0, 0, 0);
    __syncthreads();
  }
  // epilogue: optional elu+1, scatter to head-major (B, NH, S, HD)
#pragma unroll
  for (int i = 0; i < 4; ++i) {
    int r0 = rbase + wr + i * 16 + quad * 4;
#pragma unroll
    for (int j = 0; j < 4; ++j) {
      int col = cbase + wc + j * 16 + l16;
      int h = col >> 6, d = col & 63;
#pragma unroll
      for (int r = 0; r < 4; ++r) {
        float x = acc[i][j][r];
        if (z < 2) x = (x > 0.f) ? (x + 1.f) : __expf(x);
        int row = r0 + r;
        int b = row >> 11, sl = row & (S_ - 1);
        outp[((size_t)(b * NH_ + h) * S_ + sl) * HD_ + d] = (_Float16)x;
      }
    }
  }
}

// ---------------- V transpose per head: (bh, s, d) -> (bh, d, s) -----------
// grid (32, 32) block 256
__global__ __launch_bounds__(256) void v_transpose(
    const _Float16* __restrict__ vh, _Float16* __restrict__ vt) {
  int bh = blockIdx.y;
  int s0 = blockIdx.x * 64;
  __shared__ _Float16 t[64 * 72];
  int tid = threadIdx.x;
#pragma unroll
  for (int c = tid; c < 512; c += 256) {
    int r = c >> 3, cl = c & 7;
    *(half8*)&t[r * 72 + cl * 8] =
        *(const half8*)&vh[((size_t)bh * S_ + s0 + r) * 64 + cl * 8];
  }
  __syncthreads();
#pragma unroll
  for (int c = tid; c < 512; c += 256) {
    int d = c >> 3, sc = c & 7;
    half8 vv;
#pragma unroll
    for (int j = 0; j < 8; ++j) vv[j] = t[(sc * 8 + j) * 72 + d];
    *(half8*)&vt[((size_t)bh * 64 + d) * S_ + s0 + sc * 8] = vv;
  }
}

// ---------------- Flash attention ------------------------------------------
// grid (S/128=16, B*NH=32) block 256 (4 waves, 32 q-rows each), BC=128
__global__ __launch_bounds__(256, 2) void flash_attn(
    const _Float16* __restrict__ qh, const _Float16* __restrict__ kh,
    const _Float16* __restrict__ vt, const int* __restrict__ mask,
    _Float16* __restrict__ attn_out) {
  const int bh = blockIdx.y, b = bh >> 4, h = bh & 15;
  const int qbase = blockIdx.x * 128;
  const int tid = threadIdx.x, w = tid >> 6, lane = tid & 63;
  const int quad = lane >> 4, l16 = lane & 15;

  __shared__ _Float16 Kt[128 * 72];        // [key][d], stride 72
  __shared__ _Float16 Vt[64 * 136];        // [d][key], stride 136
  __shared__ _Float16 Pt[4][32 * 132];     // per-wave [qrow][key], stride 132
  __shared__ int mk[128];

  const _Float16* Q = qh + (size_t)bh * (S_ * HD_);
  const _Float16* K = kh + (size_t)bh * (S_ * HD_);
  const _Float16* Vg = vt + (size_t)bh * (HD_ * S_);

  // Q fragments (2 row-groups of 16) live in registers for the whole kernel
  half8 qf[2][2];
#pragma unroll
  for (int g = 0; g < 2; ++g) {
    int qr = qbase + w * 32 + g * 16 + l16;
    qf[g][0] = *(const half8*)&Q[qr * 64 + quad * 8];
    qf[g][1] = *(const half8*)&Q[qr * 64 + 32 + quad * 8];
  }

  floatx4 zero = {0.f, 0.f, 0.f, 0.f};
  floatx4 o[2][4];
#pragma unroll
  for (int g = 0; g < 2; ++g)
#pragma unroll
    for (int i = 0; i < 4; ++i) o[g][i] = zero;
  float mi[2][4], li[2][4];
#pragma unroll
  for (int g = 0; g < 2; ++g)
#pragma unroll
    for (int r = 0; r < 4; ++r) { mi[g][r] = -3e38f; li[g][r] = 0.f; }

  for (int kt = 0; kt < S_ / 128; ++kt) {
    const int key0 = kt * 128;
    // stage K tile (128 keys x 64 d) = 1024 half8s
#pragma unroll
    for (int c = tid; c < 1024; c += 256) {
      int row = c >> 3, cl = c & 7;
      *(half8*)&Kt[row * 72 + cl * 8] =
          *(const half8*)&K[(key0 + row) * 64 + cl * 8];
    }
    // stage V^T tile (64 d x 128 keys) = 1024 half8s
#pragma unroll
    for (int c = tid; c < 1024; c += 256) {
      int row = c >> 4, cl = c & 15;
      *(half8*)&Vt[row * 136 + cl * 8] =
          *(const half8*)&Vg[row * S_ + key0 + cl * 8];
    }
    if (tid < 128) mk[tid] = mask[b * S_ + key0 + tid];
    __syncthreads();

    // S_tile = Q @ K^T : 32 x 128 per wave (2 row-groups share K fragments)
    floatx4 sa[2][8];
#pragma unroll
    for (int g = 0; g < 2; ++g)
#pragma unroll
      for (int ct = 0; ct < 8; ++ct) sa[g][ct] = zero;
#pragma unroll
    for (int ct = 0; ct < 8; ++ct) {
      half8 bf0 = *(half8*)&Kt[(ct * 16 + l16) * 72 + quad * 8];
      half8 bf1 = *(half8*)&Kt[(ct * 16 + l16) * 72 + 32 + quad * 8];
      sa[0][ct] = __builtin_amdgcn_mfma_f32_16x16x32_f16(qf[0][0], bf0, sa[0][ct], 0, 0, 0);
      sa[0][ct] = __builtin_amdgcn_mfma_f32_16x16x32_f16(qf[0][1], bf1, sa[0][ct], 0, 0, 0);
      sa[1][ct] = __builtin_amdgcn_mfma_f32_16x16x32_f16(qf[1][0], bf0, sa[1][ct], 0, 0, 0);
      sa[1][ct] = __builtin_amdgcn_mfma_f32_16x16x32_f16(qf[1][1], bf1, sa[1][ct], 0, 0, 0);
    }
    // mask (col = ct*16 + l16)
#pragma unroll
    for (int ct = 0; ct < 8; ++ct) {
      if (mk[ct * 16 + l16] == 0) {
#pragma unroll
        for (int g = 0; g < 2; ++g) {
          sa[g][ct][0] = -1e30f; sa[g][ct][1] = -1e30f;
          sa[g][ct][2] = -1e30f; sa[g][ct][3] = -1e30f;
        }
      }
    }
    // online softmax per row (row = g*16 + quad*4 + r)
#pragma unroll
    for (int g = 0; g < 2; ++g)
#pragma unroll
      for (int r = 0; r < 4; ++r) {
        float mx = sa[g][0][r];
#pragma unroll
        for (int ct = 1; ct < 8; ++ct) mx = fmaxf(mx, sa[g][ct][r]);
        mx = fmaxf(mx, __shfl_xor(mx, 1));
        mx = fmaxf(mx, __shfl_xor(mx, 2));
        mx = fmaxf(mx, __shfl_xor(mx, 4));
        mx = fmaxf(mx, __shfl_xor(mx, 8));
        float mn = fmaxf(mi[g][r], mx);
        float alpha = __expf(mi[g][r] - mn);
        mi[g][r] = mn;
        float rs = 0.f;
#pragma unroll
        for (int ct = 0; ct < 8; ++ct) {
          float p = __expf(sa[g][ct][r] - mn);
          sa[g][ct][r] = p;
          rs += p;
        }
        rs += __shfl_xor(rs, 1);
        rs += __shfl_xor(rs, 2);
        rs += __shfl_xor(rs, 4);
        rs += __shfl_xor(rs, 8);
        li[g][r] = li[g][r] * alpha + rs;
        o[g][0][r] *= alpha; o[g][1][r] *= alpha;
        o[g][2][r] *= alpha; o[g][3][r] *= alpha;
      }
    // P: C-layout -> LDS (per-wave region; stride 132 => quads hit disjoint banks)
#pragma unroll
    for (int g = 0; g < 2; ++g)
#pragma unroll
      for (int ct = 0; ct < 8; ++ct)
#pragma unroll
        for (int r = 0; r < 4; ++r)
          Pt[w][(g * 16 + quad * 4 + r) * 132 + ct * 16 + l16] =
              (_Float16)sa[g][ct][r];
    __syncthreads();
    // O += P @ V  (V fragments shared across row-groups)
#pragma unroll
    for (int kk = 0; kk < 4; ++kk) {
      half8 pf0 = *(half8*)&Pt[w][l16 * 132 + kk * 32 + quad * 8];
      half8 pf1 = *(half8*)&Pt[w][(16 + l16) * 132 + kk * 32 + quad * 8];
#pragma unroll
      for (int ct2 = 0; ct2 < 4; ++ct2) {
        half8 vf = *(half8*)&Vt[(ct2 * 16 + l16) * 136 + kk * 32 + quad * 8];
        o[0][ct2] = __builtin_amdgcn_mfma_f32_16x16x32_f16(pf0, vf, o[0][ct2], 0, 0, 0);
        o[1][ct2] = __builtin_amdgcn_mfma_f32_16x16x32_f16(pf1, vf, o[1][ct2], 0, 0, 0);
      }
    }
    __syncthreads();
  }
  // epilogue: normalize, store (B, S, H) fp16
#pragma unroll
  for (int g = 0; g < 2; ++g)
#pragma unroll
    for (int ct2 = 0; ct2 < 4; ++ct2)
#pragma unroll
      for (int r = 0; r < 4; ++r) {
        int row = qbase + w * 32 + g * 16 + quad * 4 + r;
        int d = ct2 * 16 + l16;
        float val = o[g][ct2][r] / li[g][r];
        attn_out[((size_t)(b * S_ + row)) * H_ + h * HD_ + d] = (_Float16)val;
      }
}

// ---------------- Output GEMM: out = AO @ Wo^T (fp32 out) ------------------
// grid (8, 32) block 256, m97-style global_load_lds staging
__global__ __launch_bounds__(256) void out_gemm(
    const _Float16* __restrict__ A, const _Float16* __restrict__ W,
    float* __restrict__ out) {
  const int rbase = blockIdx.y * 128;
  const int cbase = blockIdx.x * 128;
  __shared__ _Float16 As[128 * 32];
  __shared__ _Float16 Bs[128 * 32];
  const int tid = threadIdx.x, lane = tid & 63, w = tid >> 6;
  const int quad = lane >> 4, l16 = lane & 15;
  const int wr = (w >> 1) * 64, wc = (w & 1) * 64;

  floatx4 zero = {0.f, 0.f, 0.f, 0.f};
  floatx4 acc[4][4];
#pragma unroll
  for (int i = 0; i < 4; ++i)
#pragma unroll
    for (int j = 0; j < 4; ++j) acc[i][j] = zero;

  const int srow = w * 32 + (lane >> 2);
  const int sseg = (lane & 3) * 8;
  const _Float16* Ag = A + (size_t)(rbase + srow) * H_ + sseg;
  const _Float16* Bg = W + (size_t)(cbase + srow) * H_ + sseg;

  for (int k0 = 0; k0 < H_; k0 += 32) {
    async_copy16(&As[(w * 32) * 32], Ag + k0);
    async_copy16(&As[(w * 32 + 16) * 32], Ag + 16 * H_ + k0);
    async_copy16(&Bs[(w * 32) * 32], Bg + k0);
    async_copy16(&Bs[(w * 32 + 16) * 32], Bg + 16 * H_ + k0);
    __syncthreads();
    half8 af[4], bf[4];
#pragma unroll
    for (int t = 0; t < 4; ++t)
      af[t] = *(half8*)&As[(wr + t * 16 + l16) * 32 + quad * 8];
#pragma unroll
    for (int t = 0; t < 4; ++t)
      bf[t] = *(half8*)&Bs[(wc + t * 16 + l16) * 32 + quad * 8];
#pragma unroll
    for (int i = 0; i < 4; ++i)
#pragma unroll
      for (int j = 0; j < 4; ++j)
        acc[i][j] = __builtin_amdgcn_mfma_f32_16x16x32_f16(af[i], bf[j],
                                                           acc[i][j], 0, 0, 0);
    __syncthreads();
  }
#pragma unroll
  for (int i = 0; i < 4; ++i) {
    int r0 = rbase + wr + i * 16 + quad * 4;
#pragma unroll
    for (int j = 0; j < 4; ++j) {
      int col = cbase + wc + j * 16 + l16;
#pragma unroll
      for (int r = 0; r < 4; ++r)
        out[(size_t)(r0 + r) * H_ + col] = acc[i][j][r];
    }
  }
}

extern "C" void kernel_launch(void* const* d_in, const int* in_sizes, int n_in,
                              void* d_out, int out_size, void* d_ws,
                              size_t ws_size, hipStream_t stream) {
  const float* hs = (const float*)d_in[0];
  const int* mask = (const int*)d_in[1];
  const float* Wq = (const float*)d_in[2];
  const float* Wk = (const float*)d_in[3];
  const float* Wv = (const float*)d_in[4];
  const float* Wo = (const float*)d_in[5];
  float* out = (float*)d_out;

  _Float16* p = (_Float16*)d_ws;
  _Float16* hs_h = p; p += (size_t)BS_ * H_;
  _Float16* w_h = p;  p += (size_t)4 * H_ * H_;
  _Float16* q_h = p;  p += (size_t)BS_ * H_;
  _Float16* k_h = p;  p += (size_t)BS_ * H_;
  _Float16* v_h = p;  p += (size_t)BS_ * H_;
  _Float16* v_t = p;  p += (size_t)BS_ * H_;
  _Float16* ao_h = p; p += (size_t)BS_ * H_;

  cvt_all<<<8192, 256, 0, stream>>>(hs, Wq, Wk, Wv, Wo, hs_h, w_h);
  qkv_gemm<<<dim3(8, 32, 3), 256, 0, stream>>>(hs_h, w_h, q_h, k_h, v_h);
  v_transpose<<<dim3(32, 32), 256, 0, stream>>>(v_h, v_t);
  flash_attn<<<dim3(16, 32), 256, 0, stream>>>(q_h, k_h, v_t, mask, ao_h);
  out_gemm<<<dim3(8, 32), 256, 0, stream>>>(ao_h, w_h + (size_t)3 * H_ * H_, out);
}

// Round 4
// 222.605 us; speedup vs baseline: 1.3519x; 1.2445x over previous
//
#include <hip/hip_runtime.h>

#define H_ 1024
#define NH_ 16
#define HD_ 64
#define B_ 2
#define S_ 2048
#define BS_ 4096

typedef _Float16 half8 __attribute__((ext_vector_type(8)));
typedef _Float16 half4_t __attribute__((ext_vector_type(4)));
typedef float floatx4 __attribute__((ext_vector_type(4)));

#define LOG2E 1.44269504088896f

__device__ __forceinline__ void async_copy16(void* lds, const void* g) {
  __builtin_amdgcn_global_load_lds(
      (const __attribute__((address_space(1))) unsigned int*)g,
      (__attribute__((address_space(3))) unsigned int*)lds, 16, 0, 0);
}

// ---------------- fp32 -> fp16 conversion (hs + 4 weights) ----------------
__global__ __launch_bounds__(256) void cvt_all(
    const float* __restrict__ hs, const float* __restrict__ wq,
    const float* __restrict__ wk, const float* __restrict__ wv,
    const float* __restrict__ wo,
    _Float16* __restrict__ hs_h, _Float16* __restrict__ w_h) {
  int i = blockIdx.x * 256 + threadIdx.x;
  int idx = i * 4;
  const float* src; _Float16* dst; int off;
  if (idx < BS_ * H_) {
    src = hs; dst = hs_h; off = idx;
  } else {
    int j = idx - BS_ * H_;
    int w = j >> 20;               // each weight is 2^20 elements
    off = j & ((1 << 20) - 1);
    src = (w == 0) ? wq : (w == 1) ? wk : (w == 2) ? wv : wo;
    dst = w_h + (size_t)w * (H_ * H_);
  }
  float4 f = *(const float4*)(src + off);
  half4_t o;
  o.x = (_Float16)f.x; o.y = (_Float16)f.y;
  o.z = (_Float16)f.z; o.w = (_Float16)f.w;
  *(half4_t*)(dst + off) = o;
}

// ---------------- QKV GEMM: C = A @ W^T ------------------------------------
// grid (8, 32, 3) block 256. z: 0=q (elu+1, *log2e) 1=k (elu+1) 2=v (-> v^T)
__global__ __launch_bounds__(256) void qkv_gemm(
    const _Float16* __restrict__ A, const _Float16* __restrict__ Wall,
    _Float16* __restrict__ qh, _Float16* __restrict__ kh,
    _Float16* __restrict__ vt) {
  const int z = blockIdx.z;
  const _Float16* W = Wall + (size_t)z * (H_ * H_);
  const int rbase = blockIdx.y * 128;
  const int cbase = blockIdx.x * 128;
  __shared__ _Float16 As[128 * 32];
  __shared__ _Float16 Bs[128 * 32];
  const int tid = threadIdx.x, lane = tid & 63, w = tid >> 6;
  const int quad = lane >> 4, l16 = lane & 15;
  const int wr = (w >> 1) * 64, wc = (w & 1) * 64;

  floatx4 zero = {0.f, 0.f, 0.f, 0.f};
  floatx4 acc[4][4];
#pragma unroll
  for (int i = 0; i < 4; ++i)
#pragma unroll
    for (int j = 0; j < 4; ++j) acc[i][j] = zero;

  const int srow = w * 32 + (lane >> 2);
  const int sseg = (lane & 3) * 8;
  const _Float16* Ag = A + (size_t)(rbase + srow) * H_ + sseg;
  const _Float16* Bg = W + (size_t)(cbase + srow) * H_ + sseg;

  for (int k0 = 0; k0 < H_; k0 += 32) {
    async_copy16(&As[(w * 32) * 32], Ag + k0);
    async_copy16(&As[(w * 32 + 16) * 32], Ag + 16 * H_ + k0);
    async_copy16(&Bs[(w * 32) * 32], Bg + k0);
    async_copy16(&Bs[(w * 32 + 16) * 32], Bg + 16 * H_ + k0);
    __syncthreads();
    half8 af[4], bf[4];
#pragma unroll
    for (int t = 0; t < 4; ++t)
      af[t] = *(half8*)&As[(wr + t * 16 + l16) * 32 + quad * 8];
#pragma unroll
    for (int t = 0; t < 4; ++t)
      bf[t] = *(half8*)&Bs[(wc + t * 16 + l16) * 32 + quad * 8];
#pragma unroll
    for (int i = 0; i < 4; ++i)
#pragma unroll
      for (int j = 0; j < 4; ++j)
        acc[i][j] = __builtin_amdgcn_mfma_f32_16x16x32_f16(af[i], bf[j],
                                                           acc[i][j], 0, 0, 0);
    __syncthreads();
  }
  // epilogue
#pragma unroll
  for (int i = 0; i < 4; ++i) {
    int r0 = rbase + wr + i * 16 + quad * 4;
    int b = r0 >> 11, sl0 = r0 & (S_ - 1);
#pragma unroll
    for (int j = 0; j < 4; ++j) {
      int col = cbase + wc + j * 16 + l16;
      int h = col >> 6, d = col & 63;
      if (z == 2) {
        // v: write transposed (bh, d, s) with packed 4-half stores
        half4_t pk;
#pragma unroll
        for (int r = 0; r < 4; ++r) pk[r] = (_Float16)acc[i][j][r];
        *(half4_t*)&vt[((size_t)(b * NH_ + h) * HD_ + d) * S_ + sl0] = pk;
      } else {
        _Float16* outp = (z == 0) ? qh : kh;
        float scale = (z == 0) ? LOG2E : 1.0f;
#pragma unroll
        for (int r = 0; r < 4; ++r) {
          float x = acc[i][j][r];
          x = ((x > 0.f) ? (x + 1.f) : __expf(x)) * scale;
          outp[((size_t)(b * NH_ + h) * S_ + sl0 + r) * HD_ + d] = (_Float16)x;
        }
      }
    }
  }
}

// ---------------- Flash attention ------------------------------------------
// grid (S/128=16, B*NH=32) block 512 (8 waves, 16 q-rows each), BC=128
// K/V staged via global_load_lds into XOR-swizzled unpadded LDS.
__global__ __launch_bounds__(512, 1) void flash_attn(
    const _Float16* __restrict__ qh, const _Float16* __restrict__ kh,
    const _Float16* __restrict__ vt, const int* __restrict__ mask,
    _Float16* __restrict__ attn_out) {
  const int bh = blockIdx.y, b = bh >> 4, h = bh & 15;
  const int qbase = blockIdx.x * 128;
  const int tid = threadIdx.x, w = tid >> 6, lane = tid & 63;
  const int quad = lane >> 4, l16 = lane & 15;

  __shared__ _Float16 Kt[128 * 64];     // [key][d], chunk slot = (d>>3)^(key&7)
  __shared__ _Float16 Vt[64 * 128];     // [d][key], chunk slot = (key>>3)^(d&15)
  __shared__ _Float16 Pt[8][16 * 132];  // per-wave [qrow][key], stride 132
  __shared__ int mk[128];

  const _Float16* Q = qh + (size_t)bh * (S_ * HD_);
  const _Float16* K = kh + (size_t)bh * (S_ * HD_);
  const _Float16* Vg = vt + (size_t)bh * (HD_ * S_);

  // Q fragment (16 rows per wave) lives in registers for the whole kernel
  const int qr = qbase + w * 16 + l16;
  half8 qf0 = *(const half8*)&Q[qr * 64 + quad * 8];
  half8 qf1 = *(const half8*)&Q[qr * 64 + 32 + quad * 8];

  floatx4 zero = {0.f, 0.f, 0.f, 0.f};
  floatx4 o[4];
#pragma unroll
  for (int i = 0; i < 4; ++i) o[i] = zero;
  float mi[4], li[4];
#pragma unroll
  for (int r = 0; r < 4; ++r) { mi[r] = -3e38f; li[r] = 0.f; }

  // staging addresses (constant parts)
  const int krow_off = lane >> 3;            // 0..7
  const int kslot = lane & 7;
  const int kchunk = kslot ^ (krow_off & 7); // key&7 == krow_off&7 (bases %8==0)
  const int vrow_off = lane >> 4;            // 0..3
  const int vslot = lane & 15;

  for (int kt = 0; kt < S_ / 128; ++kt) {
    const int key0 = kt * 128;
    // K tile: wave w stages keys [w*16, w*16+16), 2 instrs x 8 rows
    {
      int kl0 = w * 16;
      async_copy16(&Kt[kl0 * 64],
                   K + (size_t)(key0 + kl0 + krow_off) * 64 + kchunk * 8);
      async_copy16(&Kt[(kl0 + 8) * 64],
                   K + (size_t)(key0 + kl0 + 8 + krow_off) * 64 + kchunk * 8);
    }
    // V^T tile: wave w stages d rows [w*8, w*8+8), 2 instrs x 4 rows
    {
      int d0 = w * 8 + vrow_off;
      int c0 = vslot ^ (d0 & 15);
      async_copy16(&Vt[(w * 8) * 128], Vg + (size_t)d0 * S_ + key0 + c0 * 8);
      int d1 = d0 + 4;
      int c1 = vslot ^ (d1 & 15);
      async_copy16(&Vt[(w * 8 + 4) * 128], Vg + (size_t)d1 * S_ + key0 + c1 * 8);
    }
    if (tid < 128) mk[tid] = mask[b * S_ + key0 + tid];
    __syncthreads();

    // S_tile = Q @ K^T : 16 x 128 per wave (logits already in log2 domain)
    floatx4 sa[8];
#pragma unroll
    for (int ct = 0; ct < 8; ++ct) sa[ct] = zero;
#pragma unroll
    for (int ct = 0; ct < 8; ++ct) {
      int key = ct * 16 + l16;
      int s0 = quad ^ (l16 & 7);
      int s1 = (4 + quad) ^ (l16 & 7);
      half8 bf0 = *(half8*)&Kt[key * 64 + s0 * 8];
      half8 bf1 = *(half8*)&Kt[key * 64 + s1 * 8];
      sa[ct] = __builtin_amdgcn_mfma_f32_16x16x32_f16(qf0, bf0, sa[ct], 0, 0, 0);
      sa[ct] = __builtin_amdgcn_mfma_f32_16x16x32_f16(qf1, bf1, sa[ct], 0, 0, 0);
    }
    // mask (col = ct*16 + l16)
#pragma unroll
    for (int ct = 0; ct < 8; ++ct) {
      if (mk[ct * 16 + l16] == 0) {
        sa[ct][0] = -1e30f; sa[ct][1] = -1e30f;
        sa[ct][2] = -1e30f; sa[ct][3] = -1e30f;
      }
    }
    // online softmax per row (row = quad*4 + r), exp2 domain
#pragma unroll
    for (int r = 0; r < 4; ++r) {
      float mx = sa[0][r];
#pragma unroll
      for (int ct = 1; ct < 8; ++ct) mx = fmaxf(mx, sa[ct][r]);
      mx = fmaxf(mx, __shfl_xor(mx, 1));
      mx = fmaxf(mx, __shfl_xor(mx, 2));
      mx = fmaxf(mx, __shfl_xor(mx, 4));
      mx = fmaxf(mx, __shfl_xor(mx, 8));
      float mn = fmaxf(mi[r], mx);
      float alpha = __builtin_amdgcn_exp2f(mi[r] - mn);
      mi[r] = mn;
      float rs = 0.f;
#pragma unroll
      for (int ct = 0; ct < 8; ++ct) {
        float p = __builtin_amdgcn_exp2f(sa[ct][r] - mn);
        sa[ct][r] = p;
        rs += p;
      }
      rs += __shfl_xor(rs, 1);
      rs += __shfl_xor(rs, 2);
      rs += __shfl_xor(rs, 4);
      rs += __shfl_xor(rs, 8);
      li[r] = li[r] * alpha + rs;
      o[0][r] *= alpha; o[1][r] *= alpha;
      o[2][r] *= alpha; o[3][r] *= alpha;
    }
    // P: C-layout -> per-wave LDS region (stride 132: 2-way max, free)
#pragma unroll
    for (int ct = 0; ct < 8; ++ct)
#pragma unroll
      for (int r = 0; r < 4; ++r)
        Pt[w][(quad * 4 + r) * 132 + ct * 16 + l16] = (_Float16)sa[ct][r];
    // wave-local write->read ordering: lgkmcnt(0), vmcnt untouched (0xC07F)
    __builtin_amdgcn_s_waitcnt(0xC07F);
    // O += P @ V
#pragma unroll
    for (int kk = 0; kk < 4; ++kk) {
      half8 pf = *(half8*)&Pt[w][l16 * 132 + kk * 32 + quad * 8];
#pragma unroll
      for (int ct2 = 0; ct2 < 4; ++ct2) {
        int d = ct2 * 16 + l16;
        int vs = (kk * 4 + quad) ^ (l16 & 15);
        half8 vf = *(half8*)&Vt[d * 128 + vs * 8];
        o[ct2] = __builtin_amdgcn_mfma_f32_16x16x32_f16(pf, vf, o[ct2], 0, 0, 0);
      }
    }
    __syncthreads();
  }
  // epilogue: normalize, store (B, S, H) fp16
#pragma unroll
  for (int ct2 = 0; ct2 < 4; ++ct2)
#pragma unroll
    for (int r = 0; r < 4; ++r) {
      int row = qbase + w * 16 + quad * 4 + r;
      int d = ct2 * 16 + l16;
      float val = o[ct2][r] / li[r];
      attn_out[((size_t)(b * S_ + row)) * H_ + h * HD_ + d] = (_Float16)val;
    }
}

// ---------------- Output GEMM: out = AO @ Wo^T (fp32 out) ------------------
// grid (8, 32) block 256, global_load_lds staging
__global__ __launch_bounds__(256) void out_gemm(
    const _Float16* __restrict__ A, const _Float16* __restrict__ W,
    float* __restrict__ out) {
  const int rbase = blockIdx.y * 128;
  const int cbase = blockIdx.x * 128;
  __shared__ _Float16 As[128 * 32];
  __shared__ _Float16 Bs[128 * 32];
  const int tid = threadIdx.x, lane = tid & 63, w = tid >> 6;
  const int quad = lane >> 4, l16 = lane & 15;
  const int wr = (w >> 1) * 64, wc = (w & 1) * 64;

  floatx4 zero = {0.f, 0.f, 0.f, 0.f};
  floatx4 acc[4][4];
#pragma unroll
  for (int i = 0; i < 4; ++i)
#pragma unroll
    for (int j = 0; j < 4; ++j) acc[i][j] = zero;

  const int srow = w * 32 + (lane >> 2);
  const int sseg = (lane & 3) * 8;
  const _Float16* Ag = A + (size_t)(rbase + srow) * H_ + sseg;
  const _Float16* Bg = W + (size_t)(cbase + srow) * H_ + sseg;

  for (int k0 = 0; k0 < H_; k0 += 32) {
    async_copy16(&As[(w * 32) * 32], Ag + k0);
    async_copy16(&As[(w * 32 + 16) * 32], Ag + 16 * H_ + k0);
    async_copy16(&Bs[(w * 32) * 32], Bg + k0);
    async_copy16(&Bs[(w * 32 + 16) * 32], Bg + 16 * H_ + k0);
    __syncthreads();
    half8 af[4], bf[4];
#pragma unroll
    for (int t = 0; t < 4; ++t)
      af[t] = *(half8*)&As[(wr + t * 16 + l16) * 32 + quad * 8];
#pragma unroll
    for (int t = 0; t < 4; ++t)
      bf[t] = *(half8*)&Bs[(wc + t * 16 + l16) * 32 + quad * 8];
#pragma unroll
    for (int i = 0; i < 4; ++i)
#pragma unroll
      for (int j = 0; j < 4; ++j)
        acc[i][j] = __builtin_amdgcn_mfma_f32_16x16x32_f16(af[i], bf[j],
                                                           acc[i][j], 0, 0, 0);
    __syncthreads();
  }
#pragma unroll
  for (int i = 0; i < 4; ++i) {
    int r0 = rbase + wr + i * 16 + quad * 4;
#pragma unroll
    for (int j = 0; j < 4; ++j) {
      int col = cbase + wc + j * 16 + l16;
#pragma unroll
      for (int r = 0; r < 4; ++r)
        out[(size_t)(r0 + r) * H_ + col] = acc[i][j][r];
    }
  }
}

extern "C" void kernel_launch(void* const* d_in, const int* in_sizes, int n_in,
                              void* d_out, int out_size, void* d_ws,
                              size_t ws_size, hipStream_t stream) {
  const float* hs = (const float*)d_in[0];
  const int* mask = (const int*)d_in[1];
  const float* Wq = (const float*)d_in[2];
  const float* Wk = (const float*)d_in[3];
  const float* Wv = (const float*)d_in[4];
  const float* Wo = (const float*)d_in[5];
  float* out = (float*)d_out;

  _Float16* p = (_Float16*)d_ws;
  _Float16* hs_h = p; p += (size_t)BS_ * H_;
  _Float16* w_h = p;  p += (size_t)4 * H_ * H_;
  _Float16* q_h = p;  p += (size_t)BS_ * H_;
  _Float16* k_h = p;  p += (size_t)BS_ * H_;
  _Float16* v_t = p;  p += (size_t)BS_ * H_;
  _Float16* ao_h = p; p += (size_t)BS_ * H_;

  cvt_all<<<8192, 256, 0, stream>>>(hs, Wq, Wk, Wv, Wo, hs_h, w_h);
  qkv_gemm<<<dim3(8, 32, 3), 256, 0, stream>>>(hs_h, w_h, q_h, k_h, v_t);
  flash_attn<<<dim3(16, 32), 512, 0, stream>>>(q_h, k_h, v_t, mask, ao_h);
  out_gemm<<<dim3(8, 32), 256, 0, stream>>>(ao_h, w_h + (size_t)3 * H_ * H_, out);
}

// Round 5
// 213.864 us; speedup vs baseline: 1.4071x; 1.0409x over previous
//
#include <hip/hip_runtime.h>

#define H_ 1024
#define NH_ 16
#define HD_ 64
#define B_ 2
#define S_ 2048
#define BS_ 4096

typedef _Float16 half8 __attribute__((ext_vector_type(8)));
typedef _Float16 half4_t __attribute__((ext_vector_type(4)));
typedef float floatx4 __attribute__((ext_vector_type(4)));

#define LOG2E 1.44269504088896f

__device__ __forceinline__ void async_copy16(void* lds, const void* g) {
  __builtin_amdgcn_global_load_lds(
      (const __attribute__((address_space(1))) unsigned int*)g,
      (__attribute__((address_space(3))) unsigned int*)lds, 16, 0, 0);
}

// ---------------- fp32 -> fp16 conversion (hs + 4 weights) ----------------
__global__ __launch_bounds__(256) void cvt_all(
    const float* __restrict__ hs, const float* __restrict__ wq,
    const float* __restrict__ wk, const float* __restrict__ wv,
    const float* __restrict__ wo,
    _Float16* __restrict__ hs_h, _Float16* __restrict__ w_h) {
  int i = blockIdx.x * 256 + threadIdx.x;
  int idx = i * 4;
  const float* src; _Float16* dst; int off;
  if (idx < BS_ * H_) {
    src = hs; dst = hs_h; off = idx;
  } else {
    int j = idx - BS_ * H_;
    int w = j >> 20;
    off = j & ((1 << 20) - 1);
    src = (w == 0) ? wq : (w == 1) ? wk : (w == 2) ? wv : wo;
    dst = w_h + (size_t)w * (H_ * H_);
  }
  float4 f = *(const float4*)(src + off);
  half4_t o;
  o.x = (_Float16)f.x; o.y = (_Float16)f.y;
  o.z = (_Float16)f.z; o.w = (_Float16)f.w;
  *(half4_t*)(dst + off) = o;
}

// ---------------- QKV GEMM: C = A @ W^T ------------------------------------
// grid (8, 32, 3) block 256. z: 0=q (elu+1, *log2e) 1=k (elu+1) 2=v (-> v^T)
__global__ __launch_bounds__(256) void qkv_gemm(
    const _Float16* __restrict__ A, const _Float16* __restrict__ Wall,
    _Float16* __restrict__ qh, _Float16* __restrict__ kh,
    _Float16* __restrict__ vt) {
  const int z = blockIdx.z;
  const _Float16* W = Wall + (size_t)z * (H_ * H_);
  const int rbase = blockIdx.y * 128;
  const int cbase = blockIdx.x * 128;
  __shared__ _Float16 As[128 * 32];
  __shared__ _Float16 Bs[128 * 32];
  const int tid = threadIdx.x, lane = tid & 63, w = tid >> 6;
  const int quad = lane >> 4, l16 = lane & 15;
  const int wr = (w >> 1) * 64, wc = (w & 1) * 64;

  floatx4 zero = {0.f, 0.f, 0.f, 0.f};
  floatx4 acc[4][4];
#pragma unroll
  for (int i = 0; i < 4; ++i)
#pragma unroll
    for (int j = 0; j < 4; ++j) acc[i][j] = zero;

  const int srow = w * 32 + (lane >> 2);
  const int sseg = (lane & 3) * 8;
  const _Float16* Ag = A + (size_t)(rbase + srow) * H_ + sseg;
  const _Float16* Bg = W + (size_t)(cbase + srow) * H_ + sseg;

  for (int k0 = 0; k0 < H_; k0 += 32) {
    async_copy16(&As[(w * 32) * 32], Ag + k0);
    async_copy16(&As[(w * 32 + 16) * 32], Ag + 16 * H_ + k0);
    async_copy16(&Bs[(w * 32) * 32], Bg + k0);
    async_copy16(&Bs[(w * 32 + 16) * 32], Bg + 16 * H_ + k0);
    __syncthreads();
    half8 af[4], bf[4];
#pragma unroll
    for (int t = 0; t < 4; ++t)
      af[t] = *(half8*)&As[(wr + t * 16 + l16) * 32 + quad * 8];
#pragma unroll
    for (int t = 0; t < 4; ++t)
      bf[t] = *(half8*)&Bs[(wc + t * 16 + l16) * 32 + quad * 8];
#pragma unroll
    for (int i = 0; i < 4; ++i)
#pragma unroll
      for (int j = 0; j < 4; ++j)
        acc[i][j] = __builtin_amdgcn_mfma_f32_16x16x32_f16(af[i], bf[j],
                                                           acc[i][j], 0, 0, 0);
    __syncthreads();
  }
  // epilogue
#pragma unroll
  for (int i = 0; i < 4; ++i) {
    int r0 = rbase + wr + i * 16 + quad * 4;
    int b = r0 >> 11, sl0 = r0 & (S_ - 1);
#pragma unroll
    for (int j = 0; j < 4; ++j) {
      int col = cbase + wc + j * 16 + l16;
      int h = col >> 6, d = col & 63;
      if (z == 2) {
        half4_t pk;
#pragma unroll
        for (int r = 0; r < 4; ++r) pk[r] = (_Float16)acc[i][j][r];
        *(half4_t*)&vt[((size_t)(b * NH_ + h) * HD_ + d) * S_ + sl0] = pk;
      } else {
        _Float16* outp = (z == 0) ? qh : kh;
        float scale = (z == 0) ? LOG2E : 1.0f;
#pragma unroll
        for (int r = 0; r < 4; ++r) {
          float x = acc[i][j][r];
          x = ((x > 0.f) ? (x + 1.f) : __expf(x)) * scale;
          outp[((size_t)(b * NH_ + h) * S_ + sl0 + r) * HD_ + d] = (_Float16)x;
        }
      }
    }
  }
}

// ---------------- Flash attention ------------------------------------------
// grid (S/128=16, B*NH=32) block 256 (4 waves, 32 q-rows each), BC=128.
// K/V via global_load_lds into XOR-swizzled LDS; K/V fragments shared by
// 2 row-groups per wave (halves LDS fragment traffic per q-row).
__global__ __launch_bounds__(256, 2) void flash_attn(
    const _Float16* __restrict__ qh, const _Float16* __restrict__ kh,
    const _Float16* __restrict__ vt, const int* __restrict__ mask,
    _Float16* __restrict__ attn_out) {
  const int bh = blockIdx.y, b = bh >> 4, h = bh & 15;
  const int qbase = blockIdx.x * 128;
  const int tid = threadIdx.x, w = tid >> 6, lane = tid & 63;
  const int quad = lane >> 4, l16 = lane & 15;

  __shared__ _Float16 Kt[128 * 64];    // [key][d], slot = (d>>3)^(key&7)
  __shared__ _Float16 Vt[64 * 128];    // [d][key], slot = (key>>3)^(d&15)
  __shared__ _Float16 Pt[4][32 * 68];  // per-wave [qrow][key-half], stride 68

  const _Float16* Q = qh + (size_t)bh * (S_ * HD_);
  const _Float16* K = kh + (size_t)bh * (S_ * HD_);
  const _Float16* Vg = vt + (size_t)bh * (HD_ * S_);
  const int* Mb = mask + b * S_;

  // Q fragments (2 row-groups of 16) in registers for the whole kernel
  half8 qf[2][2];
#pragma unroll
  for (int g = 0; g < 2; ++g) {
    int qr = qbase + w * 32 + g * 16 + l16;
    qf[g][0] = *(const half8*)&Q[qr * 64 + quad * 8];
    qf[g][1] = *(const half8*)&Q[qr * 64 + 32 + quad * 8];
  }

  floatx4 zero = {0.f, 0.f, 0.f, 0.f};
  floatx4 o[2][4];
#pragma unroll
  for (int g = 0; g < 2; ++g)
#pragma unroll
    for (int i = 0; i < 4; ++i) o[g][i] = zero;
  float mi[2][4], li[2][4];
#pragma unroll
  for (int g = 0; g < 2; ++g)
#pragma unroll
    for (int r = 0; r < 4; ++r) { mi[g][r] = -3e38f; li[g][r] = 0.f; }

  // staging constants
  const int krow_off = lane >> 3;             // 0..7
  const int kslot = lane & 7;
  const int kchunk = kslot ^ (krow_off & 7);
  const int vrow_off = lane >> 4;             // 0..3
  const int vslot = lane & 15;

  for (int kt = 0; kt < S_ / 128; ++kt) {
    const int key0 = kt * 128;
    // K tile: wave w stages keys [w*32, w*32+32), 4 instrs x 8 rows
#pragma unroll
    for (int u = 0; u < 4; ++u) {
      int kl = w * 32 + u * 8;
      async_copy16(&Kt[kl * 64],
                   K + (size_t)(key0 + kl + krow_off) * 64 + kchunk * 8);
    }
    // V^T tile: wave w stages d rows [w*16, w*16+16), 4 instrs x 4 rows
#pragma unroll
    for (int u = 0; u < 4; ++u) {
      int d0 = w * 16 + u * 4 + vrow_off;
      int c0 = vslot ^ (d0 & 15);
      async_copy16(&Vt[(w * 16 + u * 4) * 128],
                   Vg + (size_t)d0 * S_ + key0 + c0 * 8);
    }
    // mask probe (2 coalesced loads; L2/L3-hot)
    int m0 = Mb[key0 + lane];
    int m1 = Mb[key0 + 64 + lane];
    __syncthreads();

    // S_tile = Q @ K^T : 32 x 128 per wave (2 groups share K fragments)
    floatx4 sa[2][8];
#pragma unroll
    for (int g = 0; g < 2; ++g)
#pragma unroll
      for (int ct = 0; ct < 8; ++ct) sa[g][ct] = zero;
    {
      int s0 = quad ^ (l16 & 7);
      int s1 = (4 + quad) ^ (l16 & 7);
#pragma unroll
      for (int ct = 0; ct < 8; ++ct) {
        int key = ct * 16 + l16;
        half8 bf0 = *(half8*)&Kt[key * 64 + s0 * 8];
        half8 bf1 = *(half8*)&Kt[key * 64 + s1 * 8];
        sa[0][ct] = __builtin_amdgcn_mfma_f32_16x16x32_f16(qf[0][0], bf0, sa[0][ct], 0, 0, 0);
        sa[0][ct] = __builtin_amdgcn_mfma_f32_16x16x32_f16(qf[0][1], bf1, sa[0][ct], 0, 0, 0);
        sa[1][ct] = __builtin_amdgcn_mfma_f32_16x16x32_f16(qf[1][0], bf0, sa[1][ct], 0, 0, 0);
        sa[1][ct] = __builtin_amdgcn_mfma_f32_16x16x32_f16(qf[1][1], bf1, sa[1][ct], 0, 0, 0);
      }
    }
    // masking — fast path skips everything when the tile is fully unmasked
    if (__any((m0 == 0) || (m1 == 0))) {
#pragma unroll
      for (int ct = 0; ct < 8; ++ct) {
        if (Mb[key0 + ct * 16 + l16] == 0) {
#pragma unroll
          for (int g = 0; g < 2; ++g) {
            sa[g][ct][0] = -1e30f; sa[g][ct][1] = -1e30f;
            sa[g][ct][2] = -1e30f; sa[g][ct][3] = -1e30f;
          }
        }
      }
    }
    // online softmax per row (row = g*16 + quad*4 + r), exp2 domain
#pragma unroll
    for (int g = 0; g < 2; ++g)
#pragma unroll
      for (int r = 0; r < 4; ++r) {
        float mx = sa[g][0][r];
#pragma unroll
        for (int ct = 1; ct < 8; ++ct) mx = fmaxf(mx, sa[g][ct][r]);
        mx = fmaxf(mx, __shfl_xor(mx, 1));
        mx = fmaxf(mx, __shfl_xor(mx, 2));
        mx = fmaxf(mx, __shfl_xor(mx, 4));
        mx = fmaxf(mx, __shfl_xor(mx, 8));
        float mn = fmaxf(mi[g][r], mx);
        float alpha = __builtin_amdgcn_exp2f(mi[g][r] - mn);
        mi[g][r] = mn;
        float rs = 0.f;
#pragma unroll
        for (int ct = 0; ct < 8; ++ct) {
          float p = __builtin_amdgcn_exp2f(sa[g][ct][r] - mn);
          sa[g][ct][r] = p;
          rs += p;
        }
        rs += __shfl_xor(rs, 1);
        rs += __shfl_xor(rs, 2);
        rs += __shfl_xor(rs, 4);
        rs += __shfl_xor(rs, 8);
        li[g][r] = li[g][r] * alpha + rs;
        o[g][0][r] *= alpha; o[g][1][r] *= alpha;
        o[g][2][r] *= alpha; o[g][3][r] *= alpha;
      }
    // PV in two key-half passes through the half-width per-wave Pt
#pragma unroll
    for (int hv = 0; hv < 2; ++hv) {
#pragma unroll
      for (int g = 0; g < 2; ++g)
#pragma unroll
        for (int c = 0; c < 4; ++c)
#pragma unroll
          for (int r = 0; r < 4; ++r)
            Pt[w][(g * 16 + quad * 4 + r) * 68 + c * 16 + l16] =
                (_Float16)sa[g][hv * 4 + c][r];
      // wave-local write->read ordering: lgkmcnt(0), vmcnt untouched
      __builtin_amdgcn_s_waitcnt(0xC07F);
#pragma unroll
      for (int kk2 = 0; kk2 < 2; ++kk2) {
        int kk = hv * 2 + kk2;
        half8 pf0 = *(half8*)&Pt[w][l16 * 68 + kk2 * 32 + quad * 8];
        half8 pf1 = *(half8*)&Pt[w][(16 + l16) * 68 + kk2 * 32 + quad * 8];
#pragma unroll
        for (int ct2 = 0; ct2 < 4; ++ct2) {
          int d = ct2 * 16 + l16;
          int vs = (kk * 4 + quad) ^ (l16 & 15);
          half8 vf = *(half8*)&Vt[d * 128 + vs * 8];
          o[0][ct2] = __builtin_amdgcn_mfma_f32_16x16x32_f16(pf0, vf, o[0][ct2], 0, 0, 0);
          o[1][ct2] = __builtin_amdgcn_mfma_f32_16x16x32_f16(pf1, vf, o[1][ct2], 0, 0, 0);
        }
      }
    }
    __syncthreads();
  }
  // epilogue: normalize, store (B, S, H) fp16
#pragma unroll
  for (int g = 0; g < 2; ++g)
#pragma unroll
    for (int ct2 = 0; ct2 < 4; ++ct2)
#pragma unroll
      for (int r = 0; r < 4; ++r) {
        int row = qbase + w * 32 + g * 16 + quad * 4 + r;
        int d = ct2 * 16 + l16;
        float val = o[g][ct2][r] / li[g][r];
        attn_out[((size_t)(b * S_ + row)) * H_ + h * HD_ + d] = (_Float16)val;
      }
}

// ---------------- Output GEMM: out = AO @ Wo^T (fp32 out) ------------------
// grid (16, 32) block 256: 128x64 tiles -> 512 blocks (2/CU)
__global__ __launch_bounds__(256) void out_gemm(
    const _Float16* __restrict__ A, const _Float16* __restrict__ W,
    float* __restrict__ out) {
  const int rbase = blockIdx.y * 128;
  const int cbase = blockIdx.x * 64;
  __shared__ _Float16 As[128 * 32];
  __shared__ _Float16 Bs[64 * 32];
  const int tid = threadIdx.x, lane = tid & 63, w = tid >> 6;
  const int quad = lane >> 4, l16 = lane & 15;

  floatx4 zero = {0.f, 0.f, 0.f, 0.f};
  floatx4 acc[2][4];
#pragma unroll
  for (int i = 0; i < 2; ++i)
#pragma unroll
    for (int j = 0; j < 4; ++j) acc[i][j] = zero;

  const int srowA = w * 32 + (lane >> 2);
  const int srowB = w * 16 + (lane >> 2);
  const int sseg = (lane & 3) * 8;
  const _Float16* Ag = A + (size_t)(rbase + srowA) * H_ + sseg;
  const _Float16* Bg = W + (size_t)(cbase + srowB) * H_ + sseg;

  for (int k0 = 0; k0 < H_; k0 += 32) {
    async_copy16(&As[(w * 32) * 32], Ag + k0);
    async_copy16(&As[(w * 32 + 16) * 32], Ag + 16 * H_ + k0);
    async_copy16(&Bs[(w * 16) * 32], Bg + k0);
    __syncthreads();
    half8 af[2], bf[4];
#pragma unroll
    for (int t = 0; t < 2; ++t)
      af[t] = *(half8*)&As[(w * 32 + t * 16 + l16) * 32 + quad * 8];
#pragma unroll
    for (int t = 0; t < 4; ++t)
      bf[t] = *(half8*)&Bs[(t * 16 + l16) * 32 + quad * 8];
#pragma unroll
    for (int i = 0; i < 2; ++i)
#pragma unroll
      for (int j = 0; j < 4; ++j)
        acc[i][j] = __builtin_amdgcn_mfma_f32_16x16x32_f16(af[i], bf[j],
                                                           acc[i][j], 0, 0, 0);
    __syncthreads();
  }
#pragma unroll
  for (int i = 0; i < 2; ++i) {
    int r0 = rbase + w * 32 + i * 16 + quad * 4;
#pragma unroll
    for (int j = 0; j < 4; ++j) {
      int col = cbase + j * 16 + l16;
#pragma unroll
      for (int r = 0; r < 4; ++r)
        out[(size_t)(r0 + r) * H_ + col] = acc[i][j][r];
    }
  }
}

extern "C" void kernel_launch(void* const* d_in, const int* in_sizes, int n_in,
                              void* d_out, int out_size, void* d_ws,
                              size_t ws_size, hipStream_t stream) {
  const float* hs = (const float*)d_in[0];
  const int* mask = (const int*)d_in[1];
  const float* Wq = (const float*)d_in[2];
  const float* Wk = (const float*)d_in[3];
  const float* Wv = (const float*)d_in[4];
  const float* Wo = (const float*)d_in[5];
  float* out = (float*)d_out;

  _Float16* p = (_Float16*)d_ws;
  _Float16* hs_h = p; p += (size_t)BS_ * H_;
  _Float16* w_h = p;  p += (size_t)4 * H_ * H_;
  _Float16* q_h = p;  p += (size_t)BS_ * H_;
  _Float16* k_h = p;  p += (size_t)BS_ * H_;
  _Float16* v_t = p;  p += (size_t)BS_ * H_;
  _Float16* ao_h = p; p += (size_t)BS_ * H_;

  cvt_all<<<8192, 256, 0, stream>>>(hs, Wq, Wk, Wv, Wo, hs_h, w_h);
  qkv_gemm<<<dim3(8, 32, 3), 256, 0, stream>>>(hs_h, w_h, q_h, k_h, v_t);
  flash_attn<<<dim3(16, 32), 256, 0, stream>>>(q_h, k_h, v_t, mask, ao_h);
  out_gemm<<<dim3(16, 32), 256, 0, stream>>>(ao_h, w_h + (size_t)3 * H_ * H_, out);
}

// Round 6
// 192.730 us; speedup vs baseline: 1.5614x; 1.1097x over previous
//
#include <hip/hip_runtime.h>

#define H_ 1024
#define NH_ 16
#define HD_ 64
#define B_ 2
#define S_ 2048
#define BS_ 4096

typedef _Float16 half8 __attribute__((ext_vector_type(8)));
typedef _Float16 half4_t __attribute__((ext_vector_type(4)));
typedef float floatx4 __attribute__((ext_vector_type(4)));

#define LOG2E 1.44269504088896f

__device__ __forceinline__ void async_copy16(void* lds, const void* g) {
  __builtin_amdgcn_global_load_lds(
      (const __attribute__((address_space(1))) unsigned int*)g,
      (__attribute__((address_space(3))) unsigned int*)lds, 16, 0, 0);
}

// ---------------- fp32 -> fp16 conversion (hs + 4 weights) ----------------
__global__ __launch_bounds__(256) void cvt_all(
    const float* __restrict__ hs, const float* __restrict__ wq,
    const float* __restrict__ wk, const float* __restrict__ wv,
    const float* __restrict__ wo,
    _Float16* __restrict__ hs_h, _Float16* __restrict__ w_h) {
  int i = blockIdx.x * 256 + threadIdx.x;
  int idx = i * 4;
  const float* src; _Float16* dst; int off;
  if (idx < BS_ * H_) {
    src = hs; dst = hs_h; off = idx;
  } else {
    int j = idx - BS_ * H_;
    int w = j >> 20;
    off = j & ((1 << 20) - 1);
    src = (w == 0) ? wq : (w == 1) ? wk : (w == 2) ? wv : wo;
    dst = w_h + (size_t)w * (H_ * H_);
  }
  float4 f = *(const float4*)(src + off);
  half4_t o;
  o.x = (_Float16)f.x; o.y = (_Float16)f.y;
  o.z = (_Float16)f.z; o.w = (_Float16)f.w;
  *(half4_t*)(dst + off) = o;
}

// ---------------- QKV GEMM: C = A @ W^T ------------------------------------
// grid (8, 32, 3) block 256. z: 0=q (elu+1, *log2e) 1=k (elu+1) 2=v (-> v^T)
__global__ __launch_bounds__(256) void qkv_gemm(
    const _Float16* __restrict__ A, const _Float16* __restrict__ Wall,
    _Float16* __restrict__ qh, _Float16* __restrict__ kh,
    _Float16* __restrict__ vt) {
  const int z = blockIdx.z;
  const _Float16* W = Wall + (size_t)z * (H_ * H_);
  const int rbase = blockIdx.y * 128;
  const int cbase = blockIdx.x * 128;
  __shared__ _Float16 As[128 * 32];
  __shared__ _Float16 Bs[128 * 32];
  const int tid = threadIdx.x, lane = tid & 63, w = tid >> 6;
  const int quad = lane >> 4, l16 = lane & 15;
  const int wr = (w >> 1) * 64, wc = (w & 1) * 64;

  floatx4 zero = {0.f, 0.f, 0.f, 0.f};
  floatx4 acc[4][4];
#pragma unroll
  for (int i = 0; i < 4; ++i)
#pragma unroll
    for (int j = 0; j < 4; ++j) acc[i][j] = zero;

  const int srow = w * 32 + (lane >> 2);
  const int sseg = (lane & 3) * 8;
  const _Float16* Ag = A + (size_t)(rbase + srow) * H_ + sseg;
  const _Float16* Bg = W + (size_t)(cbase + srow) * H_ + sseg;

  for (int k0 = 0; k0 < H_; k0 += 32) {
    async_copy16(&As[(w * 32) * 32], Ag + k0);
    async_copy16(&As[(w * 32 + 16) * 32], Ag + 16 * H_ + k0);
    async_copy16(&Bs[(w * 32) * 32], Bg + k0);
    async_copy16(&Bs[(w * 32 + 16) * 32], Bg + 16 * H_ + k0);
    __syncthreads();
    half8 af[4], bf[4];
#pragma unroll
    for (int t = 0; t < 4; ++t)
      af[t] = *(half8*)&As[(wr + t * 16 + l16) * 32 + quad * 8];
#pragma unroll
    for (int t = 0; t < 4; ++t)
      bf[t] = *(half8*)&Bs[(wc + t * 16 + l16) * 32 + quad * 8];
#pragma unroll
    for (int i = 0; i < 4; ++i)
#pragma unroll
      for (int j = 0; j < 4; ++j)
        acc[i][j] = __builtin_amdgcn_mfma_f32_16x16x32_f16(af[i], bf[j],
                                                           acc[i][j], 0, 0, 0);
    __syncthreads();
  }
  // epilogue
#pragma unroll
  for (int i = 0; i < 4; ++i) {
    int r0 = rbase + wr + i * 16 + quad * 4;
    int b = r0 >> 11, sl0 = r0 & (S_ - 1);
#pragma unroll
    for (int j = 0; j < 4; ++j) {
      int col = cbase + wc + j * 16 + l16;
      int h = col >> 6, d = col & 63;
      if (z == 2) {
        half4_t pk;
#pragma unroll
        for (int r = 0; r < 4; ++r) pk[r] = (_Float16)acc[i][j][r];
        *(half4_t*)&vt[((size_t)(b * NH_ + h) * HD_ + d) * S_ + sl0] = pk;
      } else {
        _Float16* outp = (z == 0) ? qh : kh;
        float scale = (z == 0) ? LOG2E : 1.0f;
#pragma unroll
        for (int r = 0; r < 4; ++r) {
          float x = acc[i][j][r];
          x = ((x > 0.f) ? (x + 1.f) : __expf(x)) * scale;
          outp[((size_t)(b * NH_ + h) * S_ + sl0 + r) * HD_ + d] = (_Float16)x;
        }
      }
    }
  }
}

// ---------------- Flash attention ------------------------------------------
// grid (S/128=16, B*NH=32) block 256 (4 waves, 32 q-rows each), BC=128.
// Swapped-operand scheme: QK computes S^T (mfma A=K,B=Q); P^T feeds PV
// directly from registers via 16x16x16 MFMA (no P LDS round-trip).
// K/V double-buffered via global_load_lds; ONE barrier per tile.
__global__ __launch_bounds__(256, 2) void flash_attn(
    const _Float16* __restrict__ qh, const _Float16* __restrict__ kh,
    const _Float16* __restrict__ vt, const int* __restrict__ mask,
    _Float16* __restrict__ attn_out) {
  const int bh = blockIdx.y, b = bh >> 4, h = bh & 15;
  const int qbase = blockIdx.x * 128;
  const int tid = threadIdx.x, w = tid >> 6, lane = tid & 63;
  const int quad = lane >> 4, l16 = lane & 15;

  __shared__ _Float16 Kt[2][128 * 64];  // [key][d], slot = (d>>3)^(key&7)
  __shared__ _Float16 Vt[2][64 * 128];  // [d][key], slot = (key>>3)^(d&15)

  const _Float16* Q = qh + (size_t)bh * (S_ * HD_);
  const _Float16* K = kh + (size_t)bh * (S_ * HD_);
  const _Float16* Vg = vt + (size_t)bh * (HD_ * S_);
  const int* Mb = mask + b * S_;

  // Q B-fragments (2 row-groups of 16 q) in registers for the whole kernel
  half8 qf[2][2];
#pragma unroll
  for (int g = 0; g < 2; ++g) {
    int qr = qbase + w * 32 + g * 16 + l16;
    qf[g][0] = *(const half8*)&Q[qr * 64 + quad * 8];
    qf[g][1] = *(const half8*)&Q[qr * 64 + 32 + quad * 8];
  }

  floatx4 zero = {0.f, 0.f, 0.f, 0.f};
  floatx4 o[2][4];  // O^T[d = ct2*16 + quad*4 + r][q = l16 (group g)]
#pragma unroll
  for (int g = 0; g < 2; ++g)
#pragma unroll
    for (int i = 0; i < 4; ++i) o[g][i] = zero;
  float mi[2] = {-3e38f, -3e38f}, li[2] = {0.f, 0.f};

  // staging constants
  const int krow_off = lane >> 3;             // 0..7
  const int kslot = lane & 7;
  const int kchunk = kslot ^ (krow_off & 7);
  const int vrow_off = lane >> 4;             // 0..3
  const int vslot = lane & 15;

  // prologue: stage tile 0 into buffer 0
  {
#pragma unroll
    for (int u = 0; u < 4; ++u) {
      int kl = w * 32 + u * 8;
      async_copy16(&Kt[0][kl * 64], K + (size_t)(kl + krow_off) * 64 + kchunk * 8);
    }
#pragma unroll
    for (int u = 0; u < 4; ++u) {
      int d0 = w * 16 + u * 4 + vrow_off;
      int c0 = vslot ^ (d0 & 15);
      async_copy16(&Vt[0][(w * 16 + u * 4) * 128], Vg + (size_t)d0 * S_ + c0 * 8);
    }
  }

  for (int kt = 0; kt < S_ / 128; ++kt) {
    const int key0 = kt * 128;
    const int buf = kt & 1;
    // barrier: compiler-inserted vmcnt(0) drains our DMA (issued a full tile
    // ago -> latency hidden); barrier makes all waves' DMA visible.
    __syncthreads();
    // prefetch next tile into the other buffer
    if (kt < S_ / 128 - 1) {
      const int key1 = key0 + 128;
#pragma unroll
      for (int u = 0; u < 4; ++u) {
        int kl = w * 32 + u * 8;
        async_copy16(&Kt[buf ^ 1][kl * 64],
                     K + (size_t)(key1 + kl + krow_off) * 64 + kchunk * 8);
      }
#pragma unroll
      for (int u = 0; u < 4; ++u) {
        int d0 = w * 16 + u * 4 + vrow_off;
        int c0 = vslot ^ (d0 & 15);
        async_copy16(&Vt[buf ^ 1][(w * 16 + u * 4) * 128],
                     Vg + (size_t)d0 * S_ + key1 + c0 * 8);
      }
    }
    int m0 = Mb[key0 + lane];
    int m1 = Mb[key0 + 64 + lane];

    const _Float16* Kb = &Kt[buf][0];
    const _Float16* Vb = &Vt[buf][0];

    // S^T tile: mfma(A=K-frag, B=Q-frag) -> S^T[key=ct*16+quad*4+r][q=l16]
    floatx4 sa[2][8];
#pragma unroll
    for (int g = 0; g < 2; ++g)
#pragma unroll
      for (int ct = 0; ct < 8; ++ct) sa[g][ct] = zero;
    {
      int s0 = quad ^ (l16 & 7);
      int s1 = (4 + quad) ^ (l16 & 7);
#pragma unroll
      for (int ct = 0; ct < 8; ++ct) {
        int key = ct * 16 + l16;
        half8 bf0 = *(half8*)&Kb[key * 64 + s0 * 8];
        half8 bf1 = *(half8*)&Kb[key * 64 + s1 * 8];
        sa[0][ct] = __builtin_amdgcn_mfma_f32_16x16x32_f16(bf0, qf[0][0], sa[0][ct], 0, 0, 0);
        sa[0][ct] = __builtin_amdgcn_mfma_f32_16x16x32_f16(bf1, qf[0][1], sa[0][ct], 0, 0, 0);
        sa[1][ct] = __builtin_amdgcn_mfma_f32_16x16x32_f16(bf0, qf[1][0], sa[1][ct], 0, 0, 0);
        sa[1][ct] = __builtin_amdgcn_mfma_f32_16x16x32_f16(bf1, qf[1][1], sa[1][ct], 0, 0, 0);
      }
    }
    // masking (fast path: tile fully unmasked). key = ct*16 + quad*4 + r
    if (__any((m0 == 0) || (m1 == 0))) {
#pragma unroll
      for (int ct = 0; ct < 8; ++ct)
#pragma unroll
        for (int r = 0; r < 4; ++r)
          if (Mb[key0 + ct * 16 + quad * 4 + r] == 0) {
            sa[0][ct][r] = -1e30f;
            sa[1][ct][r] = -1e30f;
          }
    }
    // online softmax per q-column (in-lane over 32 logits + 2 shuffles)
#pragma unroll
    for (int g = 0; g < 2; ++g) {
      float mx = sa[g][0][0];
#pragma unroll
      for (int ct = 0; ct < 8; ++ct)
#pragma unroll
        for (int r = 0; r < 4; ++r) mx = fmaxf(mx, sa[g][ct][r]);
      mx = fmaxf(mx, __shfl_xor(mx, 16));
      mx = fmaxf(mx, __shfl_xor(mx, 32));
      float mn = fmaxf(mi[g], mx);
      float alpha = __builtin_amdgcn_exp2f(mi[g] - mn);
      mi[g] = mn;
      float rs = 0.f;
#pragma unroll
      for (int ct = 0; ct < 8; ++ct)
#pragma unroll
        for (int r = 0; r < 4; ++r) {
          float p = __builtin_amdgcn_exp2f(sa[g][ct][r] - mn);
          sa[g][ct][r] = p;
          rs += p;
        }
      rs += __shfl_xor(rs, 16);
      rs += __shfl_xor(rs, 32);
      li[g] = li[g] * alpha + rs;
#pragma unroll
      for (int ct2 = 0; ct2 < 4; ++ct2) {
        o[g][ct2][0] *= alpha; o[g][ct2][1] *= alpha;
        o[g][ct2][2] *= alpha; o[g][ct2][3] *= alpha;
      }
    }
    // PV: O^T += mfma(A=V^T-frag, B=P^T-frag) over 8 key-chunks of 16.
    // P^T C-layout (key=quad*4+r) IS the 16x16x16 B-operand layout.
#pragma unroll
    for (int ct = 0; ct < 8; ++ct) {
      half4_t p0, p1;
#pragma unroll
      for (int r = 0; r < 4; ++r) {
        p0[r] = (_Float16)sa[0][ct][r];
        p1[r] = (_Float16)sa[1][ct][r];
      }
      int chunk = (2 * ct + (quad >> 1)) ^ l16;  // key-chunk swizzled by d&15
      int off = chunk * 8 + (quad & 1) * 4;
#pragma unroll
      for (int ct2 = 0; ct2 < 4; ++ct2) {
        int d = ct2 * 16 + l16;
        half4_t vf = *(half4_t*)&Vb[d * 128 + off];
        o[0][ct2] = __builtin_amdgcn_mfma_f32_16x16x16f16(vf, p0, o[0][ct2], 0, 0, 0);
        o[1][ct2] = __builtin_amdgcn_mfma_f32_16x16x16f16(vf, p1, o[1][ct2], 0, 0, 0);
      }
    }
  }
  // epilogue: normalize, store (B, S, H) fp16 — half4 stores (d contiguous)
#pragma unroll
  for (int g = 0; g < 2; ++g) {
    float inv = 1.0f / li[g];
    int row = qbase + w * 32 + g * 16 + l16;
#pragma unroll
    for (int ct2 = 0; ct2 < 4; ++ct2) {
      half4_t pk;
#pragma unroll
      for (int r = 0; r < 4; ++r) pk[r] = (_Float16)(o[g][ct2][r] * inv);
      int d = ct2 * 16 + quad * 4;
      *(half4_t*)&attn_out[((size_t)(b * S_ + row)) * H_ + h * HD_ + d] = pk;
    }
  }
}

// ---------------- Output GEMM: out = AO @ Wo^T (fp32 out) ------------------
// grid (16, 32) block 256: 128x64 tiles -> 512 blocks (2/CU)
__global__ __launch_bounds__(256) void out_gemm(
    const _Float16* __restrict__ A, const _Float16* __restrict__ W,
    float* __restrict__ out) {
  const int rbase = blockIdx.y * 128;
  const int cbase = blockIdx.x * 64;
  __shared__ _Float16 As[128 * 32];
  __shared__ _Float16 Bs[64 * 32];
  const int tid = threadIdx.x, lane = tid & 63, w = tid >> 6;
  const int quad = lane >> 4, l16 = lane & 15;

  floatx4 zero = {0.f, 0.f, 0.f, 0.f};
  floatx4 acc[2][4];
#pragma unroll
  for (int i = 0; i < 2; ++i)
#pragma unroll
    for (int j = 0; j < 4; ++j) acc[i][j] = zero;

  const int srowA = w * 32 + (lane >> 2);
  const int srowB = w * 16 + (lane >> 2);
  const int sseg = (lane & 3) * 8;
  const _Float16* Ag = A + (size_t)(rbase + srowA) * H_ + sseg;
  const _Float16* Bg = W + (size_t)(cbase + srowB) * H_ + sseg;

  for (int k0 = 0; k0 < H_; k0 += 32) {
    async_copy16(&As[(w * 32) * 32], Ag + k0);
    async_copy16(&As[(w * 32 + 16) * 32], Ag + 16 * H_ + k0);
    async_copy16(&Bs[(w * 16) * 32], Bg + k0);
    __syncthreads();
    half8 af[2], bf[4];
#pragma unroll
    for (int t = 0; t < 2; ++t)
      af[t] = *(half8*)&As[(w * 32 + t * 16 + l16) * 32 + quad * 8];
#pragma unroll
    for (int t = 0; t < 4; ++t)
      bf[t] = *(half8*)&Bs[(t * 16 + l16) * 32 + quad * 8];
#pragma unroll
    for (int i = 0; i < 2; ++i)
#pragma unroll
      for (int j = 0; j < 4; ++j)
        acc[i][j] = __builtin_amdgcn_mfma_f32_16x16x32_f16(af[i], bf[j],
                                                           acc[i][j], 0, 0, 0);
    __syncthreads();
  }
#pragma unroll
  for (int i = 0; i < 2; ++i) {
    int r0 = rbase + w * 32 + i * 16 + quad * 4;
#pragma unroll
    for (int j = 0; j < 4; ++j) {
      int col = cbase + j * 16 + l16;
#pragma unroll
      for (int r = 0; r < 4; ++r)
        out[(size_t)(r0 + r) * H_ + col] = acc[i][j][r];
    }
  }
}

extern "C" void kernel_launch(void* const* d_in, const int* in_sizes, int n_in,
                              void* d_out, int out_size, void* d_ws,
                              size_t ws_size, hipStream_t stream) {
  const float* hs = (const float*)d_in[0];
  const int* mask = (const int*)d_in[1];
  const float* Wq = (const float*)d_in[2];
  const float* Wk = (const float*)d_in[3];
  const float* Wv = (const float*)d_in[4];
  const float* Wo = (const float*)d_in[5];
  float* out = (float*)d_out;

  _Float16* p = (_Float16*)d_ws;
  _Float16* hs_h = p; p += (size_t)BS_ * H_;
  _Float16* w_h = p;  p += (size_t)4 * H_ * H_;
  _Float16* q_h = p;  p += (size_t)BS_ * H_;
  _Float16* k_h = p;  p += (size_t)BS_ * H_;
  _Float16* v_t = p;  p += (size_t)BS_ * H_;
  _Float16* ao_h = p; p += (size_t)BS_ * H_;

  cvt_all<<<8192, 256, 0, stream>>>(hs, Wq, Wk, Wv, Wo, hs_h, w_h);
  qkv_gemm<<<dim3(8, 32, 3), 256, 0, stream>>>(hs_h, w_h, q_h, k_h, v_t);
  flash_attn<<<dim3(16, 32), 256, 0, stream>>>(q_h, k_h, v_t, mask, ao_h);
  out_gemm<<<dim3(16, 32), 256, 0, stream>>>(ao_h, w_h + (size_t)3 * H_ * H_, out);
}